// Round 3
// baseline (2866.891 us; speedup 1.0000x reference)
//
#include <hip/hip_runtime.h>
#include <hip/hip_bf16.h>

#define EDGES 50000
#define NODES 10000

typedef __hip_bfloat16 bf16;

__device__ __forceinline__ float bf2f(bf16 v){ return __bfloat162float(v); }
__device__ __forceinline__ bf16  f2bf(float v){ return __float2bfloat16(v); }
__device__ __forceinline__ unsigned short bfbits(float f){
  bf16 h = __float2bfloat16(f);
  return *reinterpret_cast<unsigned short*>(&h);
}
__device__ __forceinline__ float silu_f(float v){ return v * (1.0f/(1.0f+__expf(-v))); }

// ---------------------------------------------------------------------------
// K1: msg[e] = wigner[e] @ x[src[e]]   (9x9 @ 9x128), write bf16
// ---------------------------------------------------------------------------
__global__ __launch_bounds__(128)
void k_gather_rot(const float* __restrict__ x, const int* __restrict__ eidx,
                  const float* __restrict__ wig, bf16* __restrict__ msg)
{
  const int e = blockIdx.x;
  const int c = threadIdx.x;
  __shared__ float wl[81];
  if (c < 81) wl[c] = wig[e*81 + c];
  const int src = eidx[e];                 // edge_index[0][e]
  const float* xp = x + (size_t)src*1152 + c;
  float xr[9];
#pragma unroll
  for (int f=0; f<9; ++f) xr[f] = xp[f*128];
  __syncthreads();
  bf16* mp = msg + (size_t)e*1152 + c;
#pragma unroll
  for (int fo=0; fo<9; ++fo){
    float a = 0.f;
#pragma unroll
    for (int f=0; f<9; ++f) a = fmaf(wl[fo*9+f], xr[f], a);
    mp[fo*128] = f2bf(a);
  }
}

// ---------------------------------------------------------------------------
// K2: rad[e] = silu(LN(x_edge@w1+b1))@w2 + b2   (one radial, TE=16)
// ---------------------------------------------------------------------------
__global__ __launch_bounds__(256)
void k_radial(const float* __restrict__ x_edge,
              const float* __restrict__ w1, const float* __restrict__ b1,
              const float* __restrict__ gm, const float* __restrict__ bt,
              const float* __restrict__ w2, const float* __restrict__ b2,
              bf16* __restrict__ ro)
{
  __shared__ float xe[16][128];
  __shared__ float h[16][128];
  __shared__ float mu_s[16], rs_s[16];
  const int t = threadIdx.x;
  const int e0 = blockIdx.x * 16;
  for (int i=0;i<8;++i){
    int lin = t + 256*i;
    int e = lin >> 7, j2 = lin & 127;
    xe[e][j2] = x_edge[(size_t)(e0+e)*128 + j2];
  }
  __syncthreads();
  const int j = t & 127, g = t >> 7;
  // h = xe @ w1 + b1
  {
    float acc[8] = {0,0,0,0,0,0,0,0};
    for (int k=0;k<128;k+=4){
      float wv0 = w1[(k+0)*128+j];
      float wv1 = w1[(k+1)*128+j];
      float wv2 = w1[(k+2)*128+j];
      float wv3 = w1[(k+3)*128+j];
#pragma unroll
      for (int e=0;e<8;++e){
        float4 xv = *(const float4*)&xe[g*8+e][k];
        acc[e] += xv.x*wv0 + xv.y*wv1 + xv.z*wv2 + xv.w*wv3;
      }
    }
    float bv = b1[j];
#pragma unroll
    for (int e=0;e<8;++e) h[g*8+e][j] = acc[e] + bv;
  }
  __syncthreads();
  // LayerNorm stats: 16 threads per edge
  {
    int e = t >> 4, p = t & 15;
    float s=0.f, ss=0.f;
#pragma unroll
    for (int i=0;i<8;++i){ float v = h[e][p+16*i]; s += v; ss += v*v; }
#pragma unroll
    for (int off=8; off>0; off>>=1){ s += __shfl_xor(s, off, 16); ss += __shfl_xor(ss, off, 16); }
    if (p==0){
      float m = s*(1.f/128.f);
      mu_s[e] = m;
      rs_s[e] = rsqrtf(fmaxf(ss*(1.f/128.f)-m*m, 0.f) + 1e-5f);
    }
  }
  __syncthreads();
  // normalize + affine + silu (in place)
  {
    float gv = gm[j], bv = bt[j];
#pragma unroll
    for (int e=0;e<8;++e){
      int ee = g*8+e;
      float v = (h[ee][j]-mu_s[ee])*rs_s[ee]*gv + bv;
      h[ee][j] = silu_f(v);
    }
  }
  __syncthreads();
  // rad = h @ w2 + b2  (128 -> 768), 192 threads x 4 cols
  if (t < 192){
    int col = t*4;
    float acc[16][4];
#pragma unroll
    for (int e=0;e<16;++e){ acc[e][0]=acc[e][1]=acc[e][2]=acc[e][3]=0.f; }
    for (int k=0;k<128;k+=4){
      float4 wv0 = *(const float4*)&w2[(k+0)*768+col];
      float4 wv1 = *(const float4*)&w2[(k+1)*768+col];
      float4 wv2 = *(const float4*)&w2[(k+2)*768+col];
      float4 wv3 = *(const float4*)&w2[(k+3)*768+col];
#pragma unroll
      for (int e=0;e<16;++e){
        float4 hv = *(const float4*)&h[e][k];
        acc[e][0] += hv.x*wv0.x + hv.y*wv1.x + hv.z*wv2.x + hv.w*wv3.x;
        acc[e][1] += hv.x*wv0.y + hv.y*wv1.y + hv.z*wv2.y + hv.w*wv3.y;
        acc[e][2] += hv.x*wv0.z + hv.y*wv1.z + hv.z*wv2.z + hv.w*wv3.z;
        acc[e][3] += hv.x*wv0.w + hv.y*wv1.w + hv.z*wv2.w + hv.w*wv3.w;
      }
    }
    float4 bv = *(const float4*)&b2[col];
#pragma unroll
    for (int e=0;e<16;++e){
      ushort4 pk;
      pk.x = bfbits(acc[e][0]+bv.x);
      pk.y = bfbits(acc[e][1]+bv.y);
      pk.z = bfbits(acc[e][2]+bv.z);
      pk.w = bfbits(acc[e][3]+bv.w);
      *reinterpret_cast<ushort4*>(&ro[(size_t)(e0+e)*768 + col]) = pk;
    }
  }
}

// ---------------------------------------------------------------------------
// K3/K4: SO2 conv (+gate when CONV1), TE=8 edges/block, in-place on msg
// ---------------------------------------------------------------------------
template<bool CONV1>
__global__ __launch_bounds__(256)
void k_so2(const bf16* __restrict__ rad,
           const float* __restrict__ w0, const float* __restrict__ b0,
           const float* __restrict__ w1, const float* __restrict__ w2,
           bf16* __restrict__ msg)
{
  __shared__ float xs[8][1152];
  __shared__ float yb[16][512];
  __shared__ float gl[8][256];
  const int t = threadIdx.x;
  const int e0 = blockIdx.x*8;
  // stage scaled features: xs[e][f*128+c] = msg * rad[S(f)*128+c]
  for (int i=0;i<36;++i){
    int lin = t + 256*i;              // 0..9215
    int e = lin / 1152;
    int rr = lin - e*1152;
    int f = rr >> 7, c = rr & 127;
    int s = (f<3) ? f : ((f<7) ? (3 + ((f+1)&1)) : 5);
    float m  = bf2f(msg[(size_t)(e0+e)*1152 + rr]);
    float rv = bf2f(rad[(size_t)(e0+e)*768 + s*128 + c]);
    xs[e][rr] = m*rv;
  }
  __syncthreads();
  // ---------- y0 = xs[:, :384] @ w0 + b0 ----------
  if (CONV1){
    if (t < 160){
      int col = t*4;                  // N0 = 640
      float acc[8][4];
#pragma unroll
      for (int e=0;e<8;++e){ acc[e][0]=acc[e][1]=acc[e][2]=acc[e][3]=0.f; }
      for (int k=0;k<384;k+=4){
        float4 wv0 = *(const float4*)&w0[(k+0)*640+col];
        float4 wv1 = *(const float4*)&w0[(k+1)*640+col];
        float4 wv2 = *(const float4*)&w0[(k+2)*640+col];
        float4 wv3 = *(const float4*)&w0[(k+3)*640+col];
#pragma unroll
        for (int e=0;e<8;++e){
          float4 xv = *(const float4*)&xs[e][k];
          acc[e][0] += xv.x*wv0.x + xv.y*wv1.x + xv.z*wv2.x + xv.w*wv3.x;
          acc[e][1] += xv.x*wv0.y + xv.y*wv1.y + xv.z*wv2.y + xv.w*wv3.y;
          acc[e][2] += xv.x*wv0.z + xv.y*wv1.z + xv.z*wv2.z + xv.w*wv3.z;
          acc[e][3] += xv.x*wv0.w + xv.y*wv1.w + xv.z*wv2.w + xv.w*wv3.w;
        }
      }
      float bvv[4] = { b0[col], b0[col+1], b0[col+2], b0[col+3] };
#pragma unroll
      for (int e=0;e<8;++e){
#pragma unroll
        for (int q=0;q<4;++q){
          float v = acc[e][q] + bvv[q];
          int cc = col+q;
          if (cc >= 384) gl[e][cc-384] = silu_f(v);     // gating, pre-silu'd
          else           ((float*)yb)[e*384+cc] = v;    // out0 raw
        }
      }
    }
    __syncthreads();
    // rows 0..2: silu(row0), rows1,2 gated by g0/g1
    for (int i=0;i<12;++i){
      int lin = t + 256*i;            // 0..3071
      int e = lin / 384, col = lin - e*384;
      float v = ((float*)yb)[e*384+col];
      int f = col >> 7, c = col & 127;
      float o = (f==0) ? silu_f(v) : v * gl[e][(f==2?128:0)+c];
      msg[(size_t)(e0+e)*1152 + col] = f2bf(o);
    }
    __syncthreads();
  } else {
    if (t < 192){
      int col = t*2;                  // N0 = 384
      float acc[8][2];
#pragma unroll
      for (int e=0;e<8;++e){ acc[e][0]=acc[e][1]=0.f; }
      for (int k=0;k<384;k+=4){
        float2 wv0 = *(const float2*)&w0[(k+0)*384+col];
        float2 wv1 = *(const float2*)&w0[(k+1)*384+col];
        float2 wv2 = *(const float2*)&w0[(k+2)*384+col];
        float2 wv3 = *(const float2*)&w0[(k+3)*384+col];
#pragma unroll
        for (int e=0;e<8;++e){
          float4 xv = *(const float4*)&xs[e][k];
          acc[e][0] += xv.x*wv0.x + xv.y*wv1.x + xv.z*wv2.x + xv.w*wv3.x;
          acc[e][1] += xv.x*wv0.y + xv.y*wv1.y + xv.z*wv2.y + xv.w*wv3.y;
        }
      }
      float2 bv = *(const float2*)&b0[col];
#pragma unroll
      for (int e=0;e<8;++e){
        ushort2 pk;
        pk.x = bfbits(acc[e][0]+bv.x);
        pk.y = bfbits(acc[e][1]+bv.y);
        *reinterpret_cast<ushort2*>(&msg[(size_t)(e0+e)*1152 + col]) = pk;
      }
    }
    __syncthreads();
  }
  // ---------- y1: 16 rows (e,m), K=256, N=512 ----------
  {
    int col2 = t*2;
    float acc[16][2];
#pragma unroll
    for (int em=0;em<16;++em){ acc[em][0]=acc[em][1]=0.f; }
    for (int k=0;k<256;k+=4){
      float2 wv0 = *(const float2*)&w1[(k+0)*512+col2];
      float2 wv1 = *(const float2*)&w1[(k+1)*512+col2];
      float2 wv2 = *(const float2*)&w1[(k+2)*512+col2];
      float2 wv3 = *(const float2*)&w1[(k+3)*512+col2];
#pragma unroll
      for (int em=0; em<16; ++em){
        int e = em>>1, m = em&1;
        float4 xv = *(const float4*)&xs[e][384 + m*256 + k];
        acc[em][0] += xv.x*wv0.x + xv.y*wv1.x + xv.z*wv2.x + xv.w*wv3.x;
        acc[em][1] += xv.x*wv0.y + xv.y*wv1.y + xv.z*wv2.y + xv.w*wv3.y;
      }
    }
#pragma unroll
    for (int em=0;em<16;++em){ yb[em][col2] = acc[em][0]; yb[em][col2+1] = acc[em][1]; }
  }
  __syncthreads();
  // combine r/i, gate, write rows 3..6
  for (int i=0;i<8;++i){
    int lin = t + 256*i;              // 0..2047 = 8e x 256j
    int e = lin >> 8, jj = lin & 255;
    float r0 = yb[e*2+0][jj],     i1 = yb[e*2+1][256+jj];
    float r1 = yb[e*2+1][jj],     i0 = yb[e*2+0][256+jj];
    float o0 = r0 - i1, o1 = r1 + i0;
    if (CONV1){ float gv = gl[e][jj]; o0 *= gv; o1 *= gv; }
    msg[(size_t)(e0+e)*1152 + 384 + jj] = f2bf(o0);
    msg[(size_t)(e0+e)*1152 + 640 + jj] = f2bf(o1);
  }
  __syncthreads();
  // ---------- y2: 16 rows (e,m), K=128, N=256 ----------
  {
    float acc[16];
#pragma unroll
    for (int em=0;em<16;++em) acc[em]=0.f;
    for (int k=0;k<128;k+=4){
      float wv0 = w2[(k+0)*256+t];
      float wv1 = w2[(k+1)*256+t];
      float wv2 = w2[(k+2)*256+t];
      float wv3 = w2[(k+3)*256+t];
#pragma unroll
      for (int em=0;em<16;++em){
        int e = em>>1, m = em&1;
        float4 xv = *(const float4*)&xs[e][896 + m*128 + k];
        acc[em] += xv.x*wv0 + xv.y*wv1 + xv.z*wv2 + xv.w*wv3;
      }
    }
    __syncthreads();   // yb rows 3..6 readers done before overwrite
#pragma unroll
    for (int em=0;em<16;++em) yb[em][t] = acc[em];
  }
  __syncthreads();
  // combine r/i, gate, write rows 7,8
  for (int i=0;i<4;++i){
    int lin = t + 256*i;              // 0..1023 = 8e x 128c
    int e = lin >> 7, c = lin & 127;
    float r0 = yb[e*2+0][c],     i1 = yb[e*2+1][128+c];
    float r1 = yb[e*2+1][c],     i0 = yb[e*2+0][128+c];
    float o0 = r0 - i1, o1 = r1 + i0;
    if (CONV1){ float gv = gl[e][128+c]; o0 *= gv; o1 *= gv; }
    msg[(size_t)(e0+e)*1152 + 896  + c] = f2bf(o0);
    msg[(size_t)(e0+e)*1152 + 1024 + c] = f2bf(o1);
  }
}

// ---------------------------------------------------------------------------
// K5: out[dst] += wigner_inv[e] @ msg[e]
// ---------------------------------------------------------------------------
__global__ __launch_bounds__(128)
void k_wiginv_scatter(const bf16* __restrict__ msg, const int* __restrict__ eidx,
                      const float* __restrict__ wiginv, float* __restrict__ out)
{
  const int e = blockIdx.x;
  const int c = threadIdx.x;
  __shared__ float wl[81];
  if (c < 81) wl[c] = wiginv[e*81 + c];
  float m[9];
#pragma unroll
  for (int r=0;r<9;++r) m[r] = bf2f(msg[(size_t)e*1152 + r*128 + c]);
  const int dst = eidx[EDGES + e];     // edge_index[1][e]
  __syncthreads();
  float* op = out + (size_t)dst*1152 + c;
#pragma unroll
  for (int f=0;f<9;++f){
    float a = 0.f;
#pragma unroll
    for (int r=0;r<9;++r) a = fmaf(wl[f*9+r], m[r], a);
    atomicAdd(op + f*128, a);
  }
}

// ---------------------------------------------------------------------------
extern "C" void kernel_launch(void* const* d_in, const int* in_sizes, int n_in,
                              void* d_out, int out_size, void* d_ws, size_t ws_size,
                              hipStream_t stream)
{
  const float* x       = (const float*)d_in[0];
  const float* x_edge  = (const float*)d_in[1];
  // d_in[2] edge_distance: unused by reference
  const int*   eidx    = (const int*)  d_in[3];
  const float* wig     = (const float*)d_in[4];
  const float* wiginv  = (const float*)d_in[5];
  const float* r1w1    = (const float*)d_in[6];
  const float* r1b1    = (const float*)d_in[7];
  const float* r1g     = (const float*)d_in[8];
  const float* r1bt    = (const float*)d_in[9];
  const float* r1w2    = (const float*)d_in[10];
  const float* r1b2    = (const float*)d_in[11];
  const float* c1w0    = (const float*)d_in[12];
  const float* c1b0    = (const float*)d_in[13];
  const float* c1w1    = (const float*)d_in[14];
  const float* c1w2    = (const float*)d_in[15];
  const float* r2w1    = (const float*)d_in[16];
  const float* r2b1    = (const float*)d_in[17];
  const float* r2g     = (const float*)d_in[18];
  const float* r2bt    = (const float*)d_in[19];
  const float* r2w2    = (const float*)d_in[20];
  const float* r2b2    = (const float*)d_in[21];
  const float* c2w0    = (const float*)d_in[22];
  const float* c2b0    = (const float*)d_in[23];
  const float* c2w1    = (const float*)d_in[24];
  const float* c2w2    = (const float*)d_in[25];
  float* out = (float*)d_out;

  // Workspace budget: msg (115.2 MB) + ONE rad buffer (76.8 MB) = 192.0 MB.
  // (Round-2 core dump was attributed to 268.8 MB exceeding ws_size.)
  char* ws = (char*)d_ws;
  bf16* msg = (bf16*)(ws);                                // E*1152*2 = 115.2 MB
  bf16* rad = (bf16*)(ws + (size_t)115200000);            // E*768*2  =  76.8 MB

  hipMemsetAsync(d_out, 0, (size_t)out_size*sizeof(float), stream);
  k_gather_rot<<<EDGES, 128, 0, stream>>>(x, eidx, wig, msg);
  k_radial<<<EDGES/16, 256, 0, stream>>>(x_edge, r1w1, r1b1, r1g, r1bt, r1w2, r1b2, rad);
  k_so2<true ><<<EDGES/8, 256, 0, stream>>>(rad, c1w0, c1b0, c1w1, c1w2, msg);
  k_radial<<<EDGES/16, 256, 0, stream>>>(x_edge, r2w1, r2b1, r2g, r2bt, r2w2, r2b2, rad);
  k_so2<false><<<EDGES/8, 256, 0, stream>>>(rad, c2w0, c2b0, c2w1, c2w2, msg);
  k_wiginv_scatter<<<EDGES, 128, 0, stream>>>(msg, eidx, wiginv, out);
}

// Round 6
// 1471.377 us; speedup vs baseline: 1.9484x; 1.9484x over previous
//
#include <hip/hip_runtime.h>
#include <hip/hip_bf16.h>

#define EDGES 50000
#define NODES 10000

typedef __hip_bfloat16 bf16;
typedef __attribute__((ext_vector_type(8))) short bf16x8v;  // 8 bf16 = 4 VGPR (MFMA A/B frag)
typedef __attribute__((ext_vector_type(4))) float f32x4;    // MFMA C/D frag

__device__ __forceinline__ float bf2f(bf16 v){ return __bfloat162float(v); }
__device__ __forceinline__ bf16  f2bf(float v){ return __float2bfloat16(v); }
__device__ __forceinline__ unsigned short f2bfu(float f){
  bf16 h = __float2bfloat16(f);
  union{ bf16 h; unsigned short s; } u; u.h = h; return u.s;
}
__device__ __forceinline__ float silu_f(float v){ return v * (1.0f/(1.0f+__expf(-v))); }

// packed bf16x2 multiply (for staging: xs = msg * rad)
__device__ __forceinline__ unsigned mul1(unsigned a, unsigned b){
  union{unsigned u; float f;} a0,a1,b0,b1;
  a0.u = (a & 0xffffu) << 16; a1.u = a & 0xffff0000u;
  b0.u = (b & 0xffffu) << 16; b1.u = b & 0xffff0000u;
  float p0 = a0.f*b0.f, p1 = a1.f*b1.f;
  return (unsigned)f2bfu(p0) | ((unsigned)f2bfu(p1) << 16);
}
__device__ __forceinline__ uint4 mulp(uint4 a, uint4 b){
  uint4 r; r.x=mul1(a.x,b.x); r.y=mul1(a.y,b.y); r.z=mul1(a.z,b.z); r.w=mul1(a.w,b.w); return r;
}

// ---------------------------------------------------------------------------
// K0: weight prep — w[K][N] f32  ->  wt[N][K] bf16  (B-frags become 16B rows)
// ---------------------------------------------------------------------------
__global__ __launch_bounds__(256)
void k_wT(const float* __restrict__ w, bf16* __restrict__ wt, int K, int N){
  __shared__ float tile[32][33];
  const int kb = blockIdx.x*32, nb = blockIdx.y*32;
  const int tx = threadIdx.x & 31, ty = threadIdx.x >> 5;   // 32 x 8
#pragma unroll
  for (int i=0;i<32;i+=8) tile[ty+i][tx] = w[(size_t)(kb+ty+i)*N + nb+tx];
  __syncthreads();
#pragma unroll
  for (int i=0;i<32;i+=8) wt[(size_t)(nb+ty+i)*K + kb+tx] = f2bf(tile[tx][ty+i]);
}

// ---------------------------------------------------------------------------
// K1: msg[e] = wigner[e] @ x[src[e]]   (9x9 @ 9x128), write bf16
// ---------------------------------------------------------------------------
__global__ __launch_bounds__(128)
void k_gather_rot(const float* __restrict__ x, const int* __restrict__ eidx,
                  const float* __restrict__ wig, bf16* __restrict__ msg)
{
  const int e = blockIdx.x;
  const int c = threadIdx.x;
  __shared__ float wl[81];
  if (c < 81) wl[c] = wig[e*81 + c];
  const int src = eidx[e];
  const float* xp = x + (size_t)src*1152 + c;
  float xr[9];
#pragma unroll
  for (int f=0; f<9; ++f) xr[f] = xp[f*128];
  __syncthreads();
  bf16* mp = msg + (size_t)e*1152 + c;
#pragma unroll
  for (int fo=0; fo<9; ++fo){
    float a = 0.f;
#pragma unroll
    for (int f=0; f<9; ++f) a = fmaf(wl[fo*9+f], xr[f], a);
    mp[fo*128] = f2bf(a);
  }
}

// ---------------------------------------------------------------------------
// K2: rad[e] = silu(LN(x_edge@w1+b1))@w2 + b2   (one radial, TE=16)
// ---------------------------------------------------------------------------
__global__ __launch_bounds__(256)
void k_radial(const float* __restrict__ x_edge,
              const float* __restrict__ w1, const float* __restrict__ b1,
              const float* __restrict__ gm, const float* __restrict__ bt,
              const float* __restrict__ w2, const float* __restrict__ b2,
              bf16* __restrict__ ro)
{
  __shared__ float xe[16][128];
  __shared__ float h[16][128];
  __shared__ float mu_s[16], rs_s[16];
  const int t = threadIdx.x;
  const int e0 = blockIdx.x * 16;
  for (int i=0;i<8;++i){
    int lin = t + 256*i;
    int e = lin >> 7, j2 = lin & 127;
    xe[e][j2] = x_edge[(size_t)(e0+e)*128 + j2];
  }
  __syncthreads();
  const int j = t & 127, g = t >> 7;
  {
    float acc[8] = {0,0,0,0,0,0,0,0};
    for (int k=0;k<128;k+=4){
      float wv0 = w1[(k+0)*128+j];
      float wv1 = w1[(k+1)*128+j];
      float wv2 = w1[(k+2)*128+j];
      float wv3 = w1[(k+3)*128+j];
#pragma unroll
      for (int e=0;e<8;++e){
        float4 xv = *(const float4*)&xe[g*8+e][k];
        acc[e] += xv.x*wv0 + xv.y*wv1 + xv.z*wv2 + xv.w*wv3;
      }
    }
    float bv = b1[j];
#pragma unroll
    for (int e=0;e<8;++e) h[g*8+e][j] = acc[e] + bv;
  }
  __syncthreads();
  {
    int e = t >> 4, p = t & 15;
    float s=0.f, ss=0.f;
#pragma unroll
    for (int i=0;i<8;++i){ float v = h[e][p+16*i]; s += v; ss += v*v; }
#pragma unroll
    for (int off=8; off>0; off>>=1){ s += __shfl_xor(s, off, 16); ss += __shfl_xor(ss, off, 16); }
    if (p==0){
      float m = s*(1.f/128.f);
      mu_s[e] = m;
      rs_s[e] = rsqrtf(fmaxf(ss*(1.f/128.f)-m*m, 0.f) + 1e-5f);
    }
  }
  __syncthreads();
  {
    float gv = gm[j], bv = bt[j];
#pragma unroll
    for (int e=0;e<8;++e){
      int ee = g*8+e;
      float v = (h[ee][j]-mu_s[ee])*rs_s[ee]*gv + bv;
      h[ee][j] = silu_f(v);
    }
  }
  __syncthreads();
  if (t < 192){
    int col = t*4;
    float acc[16][4];
#pragma unroll
    for (int e=0;e<16;++e){ acc[e][0]=acc[e][1]=acc[e][2]=acc[e][3]=0.f; }
    for (int k=0;k<128;k+=4){
      float4 wv0 = *(const float4*)&w2[(k+0)*768+col];
      float4 wv1 = *(const float4*)&w2[(k+1)*768+col];
      float4 wv2 = *(const float4*)&w2[(k+2)*768+col];
      float4 wv3 = *(const float4*)&w2[(k+3)*768+col];
#pragma unroll
      for (int e=0;e<16;++e){
        float4 hv = *(const float4*)&h[e][k];
        acc[e][0] += hv.x*wv0.x + hv.y*wv1.x + hv.z*wv2.x + hv.w*wv3.x;
        acc[e][1] += hv.x*wv0.y + hv.y*wv1.y + hv.z*wv2.y + hv.w*wv3.y;
        acc[e][2] += hv.x*wv0.z + hv.y*wv1.z + hv.z*wv2.z + hv.w*wv3.z;
        acc[e][3] += hv.x*wv0.w + hv.y*wv1.w + hv.z*wv2.w + hv.w*wv3.w;
      }
    }
    float4 bv = *(const float4*)&b2[col];
#pragma unroll
    for (int e=0;e<16;++e){
      ushort4 pk;
      pk.x = f2bfu(acc[e][0]+bv.x);
      pk.y = f2bfu(acc[e][1]+bv.y);
      pk.z = f2bfu(acc[e][2]+bv.z);
      pk.w = f2bfu(acc[e][3]+bv.w);
      *reinterpret_cast<ushort4*>(&ro[(size_t)(e0+e)*768 + col]) = pk;
    }
  }
}

// ---------------------------------------------------------------------------
// K3/K4: SO2 conv via MFMA. 32 edges/block, 4 waves, in-place on msg.
//   G0: [32 x 384] @ w0t -> N0 (640 conv1 incl. 256 gate cols / 384 conv2)
//   G1: [64 x 256] @ w1t -> 512 (col pairs (j, j+256) recombined in-lane)
//   G2: [64 x 128] @ w2t -> 256 (col pairs (j, j+128))
// LDS: bufA 32KB (phase-reused, XOR-swizzled) + gl 16KB = 48KB -> 3 blk/CU.
// D-frag layout (m89-verified): col=lane&15, row=(lane>>4)*4+reg.
// ---------------------------------------------------------------------------
template<bool CONV1>
__global__ __launch_bounds__(256, 3)
void k_so2_mfma(const bf16* __restrict__ rad,
                const bf16* __restrict__ w0t, const float* __restrict__ b0,
                const bf16* __restrict__ w1t, const bf16* __restrict__ w2t,
                bf16* __restrict__ msg)
{
  __shared__ char ldsA[32768];
  __shared__ bf16 gls[8192];          // [32 edges][256] silu(gating), conv1 only
  const int t    = threadIdx.x;
  const int lane = t & 63, wv = t >> 6;
  const int lrow = lane & 15, lhi = lane >> 4;
  const int e0 = blockIdx.x * 32;
  int evalid = EDGES - e0; if (evalid > 32) evalid = 32;

  // ---- stage A0: [32][384] bf16 = msg rows0-2 * rad[0:384], swizzled ----
#pragma unroll
  for (int i=0;i<6;++i){
    int ch = t + 256*i;                       // 0..1535
    int row = ch / 48, k0 = (ch % 48) * 8;
    int e = e0 + row;
    uint4 o = {0u,0u,0u,0u};
    if (e < EDGES){
      uint4 mz = *(const uint4*)(msg + (size_t)e*1152 + k0);
      uint4 rz = *(const uint4*)(rad + (size_t)e*768  + k0);
      o = mulp(mz, rz);
    }
    *(uint4*)(ldsA + ((row*768 + k0*2) ^ ((row&7)<<4))) = o;
  }
  __syncthreads();

  // ---- G0: K=384, N0 cols split 4 waves ----
  constexpr int NT0 = CONV1 ? 10 : 6;         // 16-col tiles per wave
  const int wcol0 = wv * NT0 * 16;
  f32x4 acc0[NT0][2];
  const f32x4 zf = {0.f,0.f,0.f,0.f};
#pragma unroll
  for (int nt=0; nt<NT0; ++nt){ acc0[nt][0]=zf; acc0[nt][1]=zf; }
  for (int ks=0; ks<12; ++ks){
    bf16x8v a0 = *(const bf16x8v*)(ldsA + (((lrow   )*768 + ks*64 + lhi*16) ^ ((lrow&7)<<4)));
    bf16x8v a1 = *(const bf16x8v*)(ldsA + (((16+lrow)*768 + ks*64 + lhi*16) ^ ((lrow&7)<<4)));
#pragma unroll
    for (int nt=0; nt<NT0; ++nt){
      int coln = wcol0 + nt*16 + lrow;
      bf16x8v b = *(const bf16x8v*)(w0t + (size_t)coln*384 + ks*32 + lhi*8);
      acc0[nt][0] = __builtin_amdgcn_mfma_f32_16x16x32_bf16(a0, b, acc0[nt][0], 0,0,0);
      acc0[nt][1] = __builtin_amdgcn_mfma_f32_16x16x32_bf16(a1, b, acc0[nt][1], 0,0,0);
    }
  }
  // gate cols -> gls (conv1)
  if (CONV1){
#pragma unroll
    for (int nt=0; nt<NT0; ++nt){
      int colb = wcol0 + nt*16;
      if (colb >= 384){
        float bc = b0[colb + lrow];
#pragma unroll
        for (int mt=0; mt<2; ++mt)
#pragma unroll
        for (int r=0; r<4; ++r){
          int el = mt*16 + lhi*4 + r;
          gls[el*256 + colb + lrow - 384] = f2bf(silu_f(acc0[nt][mt][r] + bc));
        }
      }
    }
  }
  __syncthreads();
  // out0 epilogue (rows 0-2)
#pragma unroll
  for (int nt=0; nt<NT0; ++nt){
    int colb = wcol0 + nt*16;
    if (colb < 384){
      int col = colb + lrow;
      int f = col >> 7, c = col & 127;
      float bc = b0[col];
#pragma unroll
      for (int mt=0; mt<2; ++mt)
#pragma unroll
      for (int r=0; r<4; ++r){
        int el = mt*16 + lhi*4 + r;
        if (el < evalid){
          float v = acc0[nt][mt][r] + bc;
          float o;
          if (CONV1) o = (f==0) ? silu_f(v) : v * bf2f(gls[el*256 + (f==2?128:0) + c]);
          else       o = v;
          msg[(size_t)(e0+el)*1152 + col] = f2bf(o);
        }
      }
    }
  }

  // ---- stage A1: [64][256] row=2e+m : msg[e][384+m*256+k] * rad[e][384+k] ----
#pragma unroll
  for (int i=0;i<8;++i){
    int ch = t + 256*i;                       // 0..2047
    int row = ch >> 5, k0 = (ch & 31) * 8;
    int e = e0 + (row >> 1);
    uint4 o = {0u,0u,0u,0u};
    if (e < EDGES){
      uint4 mz = *(const uint4*)(msg + (size_t)e*1152 + 384 + (row&1)*256 + k0);
      uint4 rz = *(const uint4*)(rad + (size_t)e*768  + 384 + k0);
      o = mulp(mz, rz);
    }
    *(uint4*)(ldsA + ((row*512 + k0*2) ^ ((row&7)<<4))) = o;
  }
  __syncthreads();

  // ---- G1: K=256, N=512, col pairs (jj, jj+256); 4 pairs/wave; mtiles 2+2 ----
#pragma unroll
  for (int half=0; half<2; ++half){
    f32x4 acc1[4][2][2];
#pragma unroll
    for (int p=0;p<4;++p){ acc1[p][0][0]=zf; acc1[p][0][1]=zf; acc1[p][1][0]=zf; acc1[p][1][1]=zf; }
    for (int ks=0; ks<8; ++ks){
      bf16x8v aA[2];
#pragma unroll
      for (int m2=0; m2<2; ++m2){
        int row = (half*2+m2)*16 + lrow;
        aA[m2] = *(const bf16x8v*)(ldsA + ((row*512 + ks*64 + lhi*16) ^ ((row&7)<<4)));
      }
#pragma unroll
      for (int p=0; p<4; ++p){
        int jj = wv*64 + p*16 + lrow;
        bf16x8v br = *(const bf16x8v*)(w1t + (size_t)jj*256       + ks*32 + lhi*8);
        bf16x8v bi = *(const bf16x8v*)(w1t + (size_t)(jj+256)*256 + ks*32 + lhi*8);
#pragma unroll
        for (int m2=0;m2<2;++m2){
          acc1[p][m2][0] = __builtin_amdgcn_mfma_f32_16x16x32_bf16(aA[m2], br, acc1[p][m2][0], 0,0,0);
          acc1[p][m2][1] = __builtin_amdgcn_mfma_f32_16x16x32_bf16(aA[m2], bi, acc1[p][m2][1], 0,0,0);
        }
      }
    }
    // epilogue rows 3-6: o0=r0-i1 -> 384+jj ; o1=r1+i0 -> 640+jj
#pragma unroll
    for (int p=0;p<4;++p)
#pragma unroll
    for (int m2=0;m2<2;++m2){
      int mt = half*2 + m2;
#pragma unroll
      for (int re=0;re<2;++re){
        int el = mt*8 + lhi*2 + re;
        float r0 = acc1[p][m2][0][2*re+0], r1 = acc1[p][m2][0][2*re+1];
        float i0 = acc1[p][m2][1][2*re+0], i1 = acc1[p][m2][1][2*re+1];
        float o0 = r0 - i1, o1 = r1 + i0;
        int jj = wv*64 + p*16 + lrow;
        if (CONV1){ float g = bf2f(gls[el*256 + jj]); o0 *= g; o1 *= g; }
        if (el < evalid){
          size_t base = (size_t)(e0+el)*1152;
          msg[base + 384 + jj] = f2bf(o0);
          msg[base + 640 + jj] = f2bf(o1);
        }
      }
    }
  }
  __syncthreads();

  // ---- stage A2: [64][128] row=2e+m : msg[e][896+m*128+k] * rad[e][640+k] ----
#pragma unroll
  for (int i=0;i<4;++i){
    int ch = t + 256*i;                       // 0..1023
    int row = ch >> 4, k0 = (ch & 15) * 8;
    int e = e0 + (row >> 1);
    uint4 o = {0u,0u,0u,0u};
    if (e < EDGES){
      uint4 mz = *(const uint4*)(msg + (size_t)e*1152 + 896 + (row&1)*128 + k0);
      uint4 rz = *(const uint4*)(rad + (size_t)e*768  + 640 + k0);
      o = mulp(mz, rz);
    }
    *(uint4*)(ldsA + ((row*256 + k0*2) ^ ((row&7)<<4))) = o;
  }
  __syncthreads();

  // ---- G2: K=128, N=256, col pairs (jj, jj+128); 2 pairs/wave; 4 mtiles ----
  {
    f32x4 acc2[2][4][2];
#pragma unroll
    for (int p=0;p<2;++p)
#pragma unroll
    for (int mt=0;mt<4;++mt){ acc2[p][mt][0]=zf; acc2[p][mt][1]=zf; }
    for (int ks=0; ks<4; ++ks){
      bf16x8v aA[4];
#pragma unroll
      for (int mt=0;mt<4;++mt){
        int row = mt*16 + lrow;
        aA[mt] = *(const bf16x8v*)(ldsA + ((row*256 + ks*64 + lhi*16) ^ ((row&7)<<4)));
      }
#pragma unroll
      for (int p=0;p<2;++p){
        int jj = wv*32 + p*16 + lrow;
        bf16x8v br = *(const bf16x8v*)(w2t + (size_t)jj*128       + ks*32 + lhi*8);
        bf16x8v bi = *(const bf16x8v*)(w2t + (size_t)(jj+128)*128 + ks*32 + lhi*8);
#pragma unroll
        for (int mt=0;mt<4;++mt){
          acc2[p][mt][0] = __builtin_amdgcn_mfma_f32_16x16x32_bf16(aA[mt], br, acc2[p][mt][0], 0,0,0);
          acc2[p][mt][1] = __builtin_amdgcn_mfma_f32_16x16x32_bf16(aA[mt], bi, acc2[p][mt][1], 0,0,0);
        }
      }
    }
    // epilogue rows 7,8: o0 -> 896+jj ; o1 -> 1024+jj ; gate g1=gls[128+jj]
#pragma unroll
    for (int p=0;p<2;++p)
#pragma unroll
    for (int mt=0;mt<4;++mt)
#pragma unroll
    for (int re=0;re<2;++re){
      int el = mt*8 + lhi*2 + re;
      float r0 = acc2[p][mt][0][2*re+0], r1 = acc2[p][mt][0][2*re+1];
      float i0 = acc2[p][mt][1][2*re+0], i1 = acc2[p][mt][1][2*re+1];
      float o0 = r0 - i1, o1 = r1 + i0;
      int jj = wv*32 + p*16 + lrow;
      if (CONV1){ float g = bf2f(gls[el*256 + 128 + jj]); o0 *= g; o1 *= g; }
      if (el < evalid){
        size_t base = (size_t)(e0+el)*1152;
        msg[base + 896  + jj] = f2bf(o0);
        msg[base + 1024 + jj] = f2bf(o1);
      }
    }
  }
}

// ---------------------------------------------------------------------------
// K5: out[dst] += wigner_inv[e] @ msg[e]
// ---------------------------------------------------------------------------
__global__ __launch_bounds__(128)
void k_wiginv_scatter(const bf16* __restrict__ msg, const int* __restrict__ eidx,
                      const float* __restrict__ wiginv, float* __restrict__ out)
{
  const int e = blockIdx.x;
  const int c = threadIdx.x;
  __shared__ float wl[81];
  if (c < 81) wl[c] = wiginv[e*81 + c];
  float m[9];
#pragma unroll
  for (int r=0;r<9;++r) m[r] = bf2f(msg[(size_t)e*1152 + r*128 + c]);
  const int dst = eidx[EDGES + e];
  __syncthreads();
  float* op = out + (size_t)dst*1152 + c;
#pragma unroll
  for (int f=0;f<9;++f){
    float a = 0.f;
#pragma unroll
    for (int r=0;r<9;++r) a = fmaf(wl[f*9+r], m[r], a);
    atomicAdd(op + f*128, a);
  }
}

// ---------------------------------------------------------------------------
extern "C" void kernel_launch(void* const* d_in, const int* in_sizes, int n_in,
                              void* d_out, int out_size, void* d_ws, size_t ws_size,
                              hipStream_t stream)
{
  const float* x       = (const float*)d_in[0];
  const float* x_edge  = (const float*)d_in[1];
  const int*   eidx    = (const int*)  d_in[3];
  const float* wig     = (const float*)d_in[4];
  const float* wiginv  = (const float*)d_in[5];
  const float* r1w1    = (const float*)d_in[6];
  const float* r1b1    = (const float*)d_in[7];
  const float* r1g     = (const float*)d_in[8];
  const float* r1bt    = (const float*)d_in[9];
  const float* r1w2    = (const float*)d_in[10];
  const float* r1b2    = (const float*)d_in[11];
  const float* c1w0    = (const float*)d_in[12];
  const float* c1b0    = (const float*)d_in[13];
  const float* c1w1    = (const float*)d_in[14];
  const float* c1w2    = (const float*)d_in[15];
  const float* r2w1    = (const float*)d_in[16];
  const float* r2b1    = (const float*)d_in[17];
  const float* r2g     = (const float*)d_in[18];
  const float* r2bt    = (const float*)d_in[19];
  const float* r2w2    = (const float*)d_in[20];
  const float* r2b2    = (const float*)d_in[21];
  const float* c2w0    = (const float*)d_in[22];
  const float* c2b0    = (const float*)d_in[23];
  const float* c2w1    = (const float*)d_in[24];
  const float* c2w2    = (const float*)d_in[25];
  float* out = (float*)d_out;

  // ws layout: msg 115.2MB | rad 76.8MB | bf16 [N][K] weights ~1.44MB  (<=193.5MB)
  char* ws = (char*)d_ws;
  bf16* msg  = (bf16*)(ws);
  bf16* rad  = (bf16*)(ws + (size_t)115200000);
  bf16* w0t1 = (bf16*)(ws + (size_t)192000000);   // 640x384
  bf16* w1t1 = (bf16*)(ws + (size_t)192491520);   // 512x256
  bf16* w2t1 = (bf16*)(ws + (size_t)192753664);   // 256x128
  bf16* w0t2 = (bf16*)(ws + (size_t)192819200);   // 384x384
  bf16* w1t2 = (bf16*)(ws + (size_t)193114112);   // 512x256
  bf16* w2t2 = (bf16*)(ws + (size_t)193376256);   // 256x128

  k_wT<<<dim3(12,20),256,0,stream>>>(c1w0, w0t1, 384, 640);
  k_wT<<<dim3( 8,16),256,0,stream>>>(c1w1, w1t1, 256, 512);
  k_wT<<<dim3( 4, 8),256,0,stream>>>(c1w2, w2t1, 128, 256);
  k_wT<<<dim3(12,12),256,0,stream>>>(c2w0, w0t2, 384, 384);
  k_wT<<<dim3( 8,16),256,0,stream>>>(c2w1, w1t2, 256, 512);
  k_wT<<<dim3( 4, 8),256,0,stream>>>(c2w2, w2t2, 128, 256);

  hipMemsetAsync(d_out, 0, (size_t)out_size*sizeof(float), stream);
  k_gather_rot<<<EDGES, 128, 0, stream>>>(x, eidx, wig, msg);
  k_radial<<<EDGES/16, 256, 0, stream>>>(x_edge, r1w1, r1b1, r1g, r1bt, r1w2, r1b2, rad);
  k_so2_mfma<true ><<<(EDGES+31)/32, 256, 0, stream>>>(rad, w0t1, c1b0, w1t1, w2t1, msg);
  k_radial<<<EDGES/16, 256, 0, stream>>>(x_edge, r2w1, r2b1, r2g, r2bt, r2w2, r2b2, rad);
  k_so2_mfma<false><<<(EDGES+31)/32, 256, 0, stream>>>(rad, w0t2, c2b0, w1t2, w2t2, msg);
  k_wiginv_scatter<<<EDGES, 128, 0, stream>>>(msg, eidx, wiginv, out);
}